// Round 11
// baseline (588.957 us; speedup 1.0000x reference)
//
#include <hip/hip_runtime.h>
#include <math.h>

// Problem constants
#define NB 32
#define NC 64          // CODE_DIM
#define NK 2048
#define NCODES 1024
#define NVEC (NB*NK)          // 65536 vectors
#define NELEM (NB*NC*NK)      // 4194304 elements
#define NBLK (NVEC/64)        // 1024 blocks

#define MARGIN 1.5e-3f        // rigorous bf16-proxy bound (validated R5)
#define CAP 32

// ws layout (bytes)
#define WS_HIST  0            // int[1024]      = 4096
#define WS_CBN32 4096         // float[1024]    = 4096
#define WS_PART  8192         // double[1024]   = 8192
#define WS_CBBF  32768        // __bf16[65536]  = 131072

typedef __bf16 bf16x8 __attribute__((ext_vector_type(8)));
typedef float  f32x4  __attribute__((ext_vector_type(4)));
#define MFMA16(A, B, ACC) __builtin_amdgcn_mfma_f32_16x16x32_bf16(A, B, ACC, 0, 0, 0)

// --- codebook prep: numpy-exact fp32 norms (same summation order as validated
// version -> bit-identical n32) + bf16 copy; block 0 zeroes hist. ------------
__global__ void k_cbprep(const float* __restrict__ cb, float* __restrict__ n32,
                         __bf16* __restrict__ cbbf, int* __restrict__ hist) {
    const int t = threadIdx.x;
    const int j = blockIdx.x * 64 + t;   // 16 x 64 = 1024
    if (blockIdx.x == 0) {
        int4 z4; z4.x = 0; z4.y = 0; z4.z = 0; z4.w = 0;
#pragma unroll
        for (int i = 0; i < 4; i++) ((int4*)hist)[t * 4 + i] = z4;
    }
    const float* cr = cb + (size_t)j * NC;
    float x[64];
#pragma unroll
    for (int i = 0; i < 16; i++) {
        f32x4 tv = *(const f32x4*)(cr + 4 * i);
        x[4*i+0] = tv[0]; x[4*i+1] = tv[1]; x[4*i+2] = tv[2]; x[4*i+3] = tv[3];
    }
    // EXACT same chain as validated version (order preserved)
    float r[8];
#pragma unroll
    for (int q = 0; q < 8; q++) r[q] = __fmul_rn(x[q], x[q]);
#pragma unroll
    for (int i = 8; i < 64; i += 8)
#pragma unroll
        for (int q = 0; q < 8; q++)
            r[q] = __fadd_rn(r[q], __fmul_rn(x[i + q], x[i + q]));
    float s01 = __fadd_rn(r[0], r[1]), s23 = __fadd_rn(r[2], r[3]);
    float s45 = __fadd_rn(r[4], r[5]), s67 = __fadd_rn(r[6], r[7]);
    n32[j] = __fadd_rn(__fadd_rn(s01, s23), __fadd_rn(s45, s67));
    __bf16* br = cbbf + (size_t)j * NC;
#pragma unroll
    for (int i = 0; i < 8; i++) {
        bf16x8 o;
#pragma unroll
        for (int q = 0; q < 8; q++) o[q] = (__bf16)x[8*i + q];
        *(bf16x8*)(br + 8*i) = o;
    }
}

// --- fused VQ: single-MFMA-pass, spill-free via early af death ---------------
// Block: 256 thr = 4 waves; 64 vectors; grid 1024 (measured-best shape).
// R10 LESSON: the (min1,min2,idx1) single-pass was correct and halved MFMA,
// but demand (~130-150 VGPR: af live across the in-kernel fallback MFMA pass)
// exceeded the 128 cap of launch_bounds(256,4) -> compiler spilled (~22MB
// scratch traffic, VGPR collapsed to 64). FIX: shrink demand, don't raise the
// cap (cap 256 would risk VGPR>128 -> 2 blk/CU, the R1 regression):
//  (1) NO fallback MFMA pass. If a lane's min2 <= gthr (>=2 near-ties in one
//      lane-column, ~never at MARGIN=1.5e-3), flag the vector and let the
//      rescore take its existing exact FULL-SCAN path (cc=CAP+1): bit-exact
//      for all 1024 codes with the validated chain + np tie rule. af now dies
//      at end of pass 1 -> peak ~= 32(af)+48(track)+16(B)+addr < 128.
//  (2) unroll 2 on the tile loop (halves in-flight B-frags vs unroll 4).
// Candidate completeness: candidates = {idx1 | min1 <= gthr} per lane-column
// (strict-lt update -> first-wins ties) is the full margin set unless some
// lane's min2 <= gthr -- exactly the flagged case. Correct in all cases.
// Other banked lessons: R1/R3/R4/R5/R6/R8 (journal). Exact rescore chain and
// separate k_final dispatch untouched (bit-exact, validated).
// MFMA 16x16x32 bf16 layout (validated R5): A[m=lane&15][k=quad*8+j];
// B[n=lane&15][k=quad*8+j]; D col=lane&15 (code), row=quad*4+reg (vector).
__launch_bounds__(256, 4)
__global__ void k_vq(const float* __restrict__ ze, const float* __restrict__ cb,
                     const float* __restrict__ n32, const __bf16* __restrict__ cbbf,
                     int* __restrict__ hist, float* __restrict__ codes_f,
                     float* __restrict__ outq, double* __restrict__ part) {
    __shared__ float wmin[64][5];            // padded minor (bank spread)
    __shared__ float gthr[64];
    __shared__ int cnt[64];
    __shared__ int needv[64];
    __shared__ int cand[64][CAP + 1];        // padded
    __shared__ unsigned long long keys2[64][5];  // padded
    __shared__ int codearr[64];
    __shared__ double lsd[4];

    const int t = threadIdx.x;
    const int L = t & 63;
    const int w = t >> 6;            // wave 0..3
    const int quad = L >> 4;
    const int col = L & 15;
    const int vec0 = blockIdx.x * 64;
    const int b = vec0 >> 11;
    const int k0 = vec0 & (NK - 1);
    const float* zbase = ze + (size_t)b * NC * NK + k0;

    // ---- A-frags for all 64 vectors (reg-resident, 32 VGPR; die after p1) --
    bf16x8 af[4][2];
#pragma unroll
    for (int vt = 0; vt < 4; vt++)
#pragma unroll
        for (int kt = 0; kt < 2; kt++)
#pragma unroll
            for (int j = 0; j < 8; j++)
                af[vt][kt][j] =
                    (__bf16)zbase[(size_t)(kt*32 + quad*8 + j) * NK + vt*16 + col];

    // ---- single pass: per-lane (min1, min2, idx1) over wave's 256 codes ----
    float m1[4][4], m2[4][4];
    int   i1[4][4];
#pragma unroll
    for (int vt = 0; vt < 4; vt++)
#pragma unroll
        for (int r = 0; r < 4; r++) {
            m1[vt][r] = 1e30f; m2[vt][r] = 1e30f; i1[vt][r] = 0;
        }
#pragma unroll 2
    for (int tile = 0; tile < 16; tile++) {   // unroll 2: cap live B-regs
        const __bf16* brow = cbbf + (size_t)(w*256 + tile*16 + col) * NC + quad*8;
        bf16x8 b0 = *(const bf16x8*)(brow);
        bf16x8 b1 = *(const bf16x8*)(brow + 32);
        float nvv = n32[w*256 + tile*16 + col];
        const int code = w*256 + tile*16 + col;
#pragma unroll
        for (int vt = 0; vt < 4; vt++) {   // 4 independent MFMA chains (ILP)
            f32x4 acc = {0.f, 0.f, 0.f, 0.f};
            acc = MFMA16(af[vt][0], b0, acc);
            acc = MFMA16(af[vt][1], b1, acc);
#pragma unroll
            for (int r = 0; r < 4; r++) {
                float pd = __fmaf_rn(-2.f, acc[r], nvv);  // == sub(nvv,mul(2,acc))
                bool lt = pd < m1[vt][r];                 // strict: first-wins ties
                float nm2 = fminf(m2[vt][r], pd);
                m2[vt][r] = lt ? m1[vt][r] : nm2;
                i1[vt][r] = lt ? code : i1[vt][r];
                m1[vt][r] = lt ? pd : m1[vt][r];
            }
        }
    }
    // one-time cross-col reduce of min1 (value only; idx resolved by rescore)
#pragma unroll
    for (int vt = 0; vt < 4; vt++)
#pragma unroll
        for (int r = 0; r < 4; r++) {
            float pm = m1[vt][r];
            pm = fminf(pm, __shfl_xor(pm, 1, 16));
            pm = fminf(pm, __shfl_xor(pm, 2, 16));
            pm = fminf(pm, __shfl_xor(pm, 4, 16));
            pm = fminf(pm, __shfl_xor(pm, 8, 16));
            if (col == 0) wmin[vt*16 + quad*4 + r][w] = pm;
        }
    __syncthreads();

    if (t < 64) {
        float g = wmin[t][0];
#pragma unroll
        for (int ww = 1; ww < 4; ww++) g = fminf(g, wmin[t][ww]);
        gthr[t] = g + MARGIN;
        cnt[t] = 0;
        needv[t] = 0;
    }
    __syncthreads();

    // ---- candidate insertion from registers (no second codebook pass) ------
    // >=2 near-ties in one lane-column -> flag vector for exact full scan.
#pragma unroll
    for (int vt = 0; vt < 4; vt++)
#pragma unroll
        for (int r = 0; r < 4; r++) {
            const int m = vt*16 + quad*4 + r;
            const float thr = gthr[m];
            if (m1[vt][r] <= thr) {
                int slot = atomicAdd(&cnt[m], 1);
                if (slot < CAP) cand[m][slot] = i1[vt][r];
            }
            if (m2[vt][r] <= thr) needv[m] = 1;
        }
    __syncthreads();

    // ---- exact rescore: 4 threads/vector, validated bit-exact fp32 chain ---
    {
        const int v = L;           // vector; this thread handles part w
        // t1 = np.sum(z*z), numpy-exact (redundant x4, bit-identical -- R2)
        float rr[8];
#pragma unroll
        for (int q = 0; q < 8; q++) {
            float xx = zbase[(size_t)q * NK + v];
            rr[q] = __fmul_rn(xx, xx);
        }
#pragma unroll
        for (int i = 8; i < 64; i += 8)
#pragma unroll
            for (int q = 0; q < 8; q++) {
                float xx = zbase[(size_t)(i + q) * NK + v];
                rr[q] = __fadd_rn(rr[q], __fmul_rn(xx, xx));
            }
        float s01 = __fadd_rn(rr[0], rr[1]), s23 = __fadd_rn(rr[2], rr[3]);
        float s45 = __fadd_rn(rr[4], rr[5]), s67 = __fadd_rn(rr[6], rr[7]);
        float t1 = __fadd_rn(__fadd_rn(s01, s23), __fadd_rn(s45, s67));

        int cc = needv[v] ? (CAP + 1) : cnt[v];   // flagged -> exact full scan
        unsigned long long kmin = 0xFFFFFFFFFFFFFFFFULL;
        if (cc <= CAP) {
            for (int si = w; si < cc; si += 4) {
                int j = cand[v][si];
                const float* cr = cb + (size_t)j * NC;
                float a = 0.f;
#pragma unroll
                for (int c = 0; c < NC; c++)
                    a = __fmaf_rn(zbase[(size_t)c * NK + v], cr[c], a);
                float d = __fmaf_rn(-2.f, a, __fadd_rn(t1, n32[j]));
                unsigned long long key =
                    ((unsigned long long)__float_as_uint(d) << 32) | (unsigned int)j;
                if (key < kmin) kmin = key;
            }
        } else {   // exact full scan split over 4 threads (bit-exact, np rule)
            for (int j = w * 256; j < (w + 1) * 256; j++) {
                const float* cr = cb + (size_t)j * NC;
                float a = 0.f;
#pragma unroll
                for (int c = 0; c < NC; c++)
                    a = __fmaf_rn(zbase[(size_t)c * NK + v], cr[c], a);
                float d = __fmaf_rn(-2.f, a, __fadd_rn(t1, n32[j]));
                unsigned long long key =
                    ((unsigned long long)__float_as_uint(d) << 32) | (unsigned int)j;
                if (key < kmin) kmin = key;
            }
        }
        keys2[v][w] = kmin;
    }
    __syncthreads();

    if (t < 64) {   // merge 4 partial keys: min dist, ties -> min idx (np rule)
        unsigned long long kmin = keys2[t][0];
#pragma unroll
        for (int ww = 1; ww < 4; ww++) {
            unsigned long long kk = keys2[t][ww];
            if (kk < kmin) kmin = kk;
        }
        int code = (int)(kmin & 0xFFFFFFFFu);
        codearr[t] = code;
        codes_f[vec0 + t] = (float)code;
        atomicAdd(&hist[code], 1);
    }
    __syncthreads();

    // ---- quant epilogue: float4; per c-row 16 thr x 16B = 256B contiguous --
    double s = 0.0;
    float* ob = outq + (size_t)b * NC * NK + k0;
    const int c0 = t >> 4;             // 0..15
    const int v0 = (t & 15) * 4;       // 0,4,..,60
    int cds[4];
#pragma unroll
    for (int u = 0; u < 4; u++) cds[u] = codearr[v0 + u];
#pragma unroll
    for (int half = 0; half < 4; half++) {
        const int c = c0 + half * 16;
        f32x4 zv = *(const f32x4*)(zbase + (size_t)c * NK + v0);
        f32x4 ov;
#pragma unroll
        for (int u = 0; u < 4; u++) {
            float qv = cb[(size_t)cds[u] * NC + c];
            ov[u] = __fadd_rn(zv[u], __fsub_rn(qv, zv[u]));
            double d = (double)qv - (double)zv[u];
            s += d * d;
        }
        *(f32x4*)(ob + (size_t)c * NK + v0) = ov;
    }
    for (int off = 32; off; off >>= 1) s += __shfl_down(s, off);
    if (L == 0) lsd[w] = s;
    __syncthreads();
    if (t == 0) part[blockIdx.x] = lsd[0] + lsd[1] + lsd[2] + lsd[3];
}

// --- final scalars: loss_vq and perplexity (separate dispatch: R8 lesson) ---
__launch_bounds__(1024)
__global__ void k_final(const double* __restrict__ part, const int* __restrict__ hist,
                        float* __restrict__ out) {
    int t = threadIdx.x;                         // 1024 threads = NBLK partials
    double vL = part[t];
    double p = (double)hist[t] * (1.0 / (double)NVEC);
    double vE = p * log(p + 1e-10);
    for (int off = 32; off; off >>= 1) {
        vL += __shfl_down(vL, off);
        vE += __shfl_down(vE, off);
    }
    __shared__ double lsL[16], lsE[16];
    int lane = t & 63, wv = t >> 6;
    if (lane == 0) { lsL[wv] = vL; lsE[wv] = vE; }
    __syncthreads();
    if (t == 0) {
        double SL = 0.0, SE = 0.0;
        for (int i = 0; i < 16; i++) { SL += lsL[i]; SE += lsE[i]; }
        double loss_cb = SL / (double)NELEM;     // == loss_commit numerically
        out[NELEM + NVEC]     = (float)(loss_cb + 0.25 * loss_cb);
        out[NELEM + NVEC + 1] = (float)exp(-SE);
    }
}

extern "C" void kernel_launch(void* const* d_in, const int* in_sizes, int n_in,
                              void* d_out, int out_size, void* d_ws, size_t ws_size,
                              hipStream_t stream) {
    const float* ze = (const float*)d_in[0];
    const float* cb = (const float*)d_in[1];
    float* out = (float*)d_out;
    char* ws = (char*)d_ws;

    int*    hist = (int*)(ws + WS_HIST);
    float*  n32  = (float*)(ws + WS_CBN32);
    double* part = (double*)(ws + WS_PART);
    __bf16* cbbf = (__bf16*)(ws + WS_CBBF);

    float* zq      = out;                 // (32, 64, 2048)
    float* codes_f = out + NELEM;         // (32, 2048) as float

    k_cbprep<<<16, 64, 0, stream>>>(cb, n32, cbbf, hist);   // also zeroes hist
    k_vq<<<NBLK, 256, 0, stream>>>(ze, cb, n32, cbbf, hist, codes_f, zq, part);
    k_final<<<1, 1024, 0, stream>>>(part, hist, out);
}

// Round 12
// 202.155 us; speedup vs baseline: 2.9134x; 2.9134x over previous
//
#include <hip/hip_runtime.h>
#include <math.h>

// Problem constants
#define NB 32
#define NC 64          // CODE_DIM
#define NK 2048
#define NCODES 1024
#define NVEC (NB*NK)          // 65536 vectors
#define NELEM (NB*NC*NK)      // 4194304 elements
#define NBLK (NVEC/64)        // 1024 blocks

#define MARGIN 1.5e-3f        // rigorous bf16-proxy bound (validated R5)
#define CAP 32

// ws layout (bytes)
#define WS_HIST  0            // int[1024]      = 4096
#define WS_CBN32 4096         // float[1024]    = 4096
#define WS_PART  8192         // double[1024]   = 8192
#define WS_CBBF  32768        // __bf16[65536]  = 131072

typedef __bf16 bf16x8 __attribute__((ext_vector_type(8)));
typedef float  f32x4  __attribute__((ext_vector_type(4)));
#define MFMA16(A, B, ACC) __builtin_amdgcn_mfma_f32_16x16x32_bf16(A, B, ACC, 0, 0, 0)

// --- codebook prep: numpy-exact fp32 norms (same summation order as validated
// version -> bit-identical n32) + bf16 copy; block 0 zeroes hist. ------------
__global__ void k_cbprep(const float* __restrict__ cb, float* __restrict__ n32,
                         __bf16* __restrict__ cbbf, int* __restrict__ hist) {
    const int t = threadIdx.x;
    const int j = blockIdx.x * 64 + t;   // 16 x 64 = 1024
    if (blockIdx.x == 0) {
        int4 z4; z4.x = 0; z4.y = 0; z4.z = 0; z4.w = 0;
#pragma unroll
        for (int i = 0; i < 4; i++) ((int4*)hist)[t * 4 + i] = z4;
    }
    const float* cr = cb + (size_t)j * NC;
    float x[64];
#pragma unroll
    for (int i = 0; i < 16; i++) {
        f32x4 tv = *(const f32x4*)(cr + 4 * i);
        x[4*i+0] = tv[0]; x[4*i+1] = tv[1]; x[4*i+2] = tv[2]; x[4*i+3] = tv[3];
    }
    // EXACT same chain as validated version (order preserved)
    float r[8];
#pragma unroll
    for (int q = 0; q < 8; q++) r[q] = __fmul_rn(x[q], x[q]);
#pragma unroll
    for (int i = 8; i < 64; i += 8)
#pragma unroll
        for (int q = 0; q < 8; q++)
            r[q] = __fadd_rn(r[q], __fmul_rn(x[i + q], x[i + q]));
    float s01 = __fadd_rn(r[0], r[1]), s23 = __fadd_rn(r[2], r[3]);
    float s45 = __fadd_rn(r[4], r[5]), s67 = __fadd_rn(r[6], r[7]);
    n32[j] = __fadd_rn(__fadd_rn(s01, s23), __fadd_rn(s45, s67));
    __bf16* br = cbbf + (size_t)j * NC;
#pragma unroll
    for (int i = 0; i < 8; i++) {
        bf16x8 o;
#pragma unroll
        for (int q = 0; q < 8; q++) o[q] = (__bf16)x[8*i + q];
        *(bf16x8*)(br + 8*i) = o;
    }
}

// --- fused VQ: R9-validated two-pass + phase-boundary load hoisting ----------
// Block: 256 thr = 4 waves; 64 vectors; grid 1024 (measured-best shape; k_vq
// 62.8us, VGPR 56, zero spills at R9). R10/R11 LESSONS: single-pass capture
// is a dead end -- halving MFMA+L2 streaming changed duration ~0 (R10), and a
// per-vector serial-scan fallback is a ~500us block straggler (R11). The
// kernel is NOT pass-2-bound; it is phase-latency-bound (sum of serial phase
// latencies between 6 barriers at only 4 blocks/CU).
// NEW vs R9 (pure load reordering, bit-identical arithmetic):
//  (1) t1 (exact np z*z chain) computed at kernel START -- its 64 coalesced
//      loads overlap af-build and pass-1 compute instead of sitting behind 3
//      barriers on the rescore critical path. Result kept in 1 VGPR.
//  (2) epilogue z re-read (4x f32x4, code-independent) issued BEFORE the
//      rescore phase; values consumed after codes are known. ~16 VGPR for the
//      duration of rescore; latency hides under candidate-dot chains.
// Banked: R1 (8-wave blocks), R3 (LDS z-staging), R4/R5 (VGPR caps < live set
// -> spills), R6 (32-vec blocks), R8 (per-block device fence = L2 writeback).
// MFMA 16x16x32 bf16 layout (validated R5): A[m=lane&15][k=quad*8+j];
// B[n=lane&15][k=quad*8+j]; D col=lane&15 (code), row=quad*4+reg (vector).
__launch_bounds__(256, 4)
__global__ void k_vq(const float* __restrict__ ze, const float* __restrict__ cb,
                     const float* __restrict__ n32, const __bf16* __restrict__ cbbf,
                     int* __restrict__ hist, float* __restrict__ codes_f,
                     float* __restrict__ outq, double* __restrict__ part) {
    __shared__ float wmin[64][5];            // padded minor (bank spread)
    __shared__ float gthr[64];
    __shared__ int cnt[64];
    __shared__ int cand[64][CAP + 1];        // padded
    __shared__ unsigned long long keys2[64][5];  // padded
    __shared__ int codearr[64];
    __shared__ double lsd[4];

    const int t = threadIdx.x;
    const int L = t & 63;
    const int w = t >> 6;            // wave 0..3
    const int quad = L >> 4;
    const int col = L & 15;
    const int vec0 = blockIdx.x * 64;
    const int b = vec0 >> 11;
    const int k0 = vec0 & (NK - 1);
    const float* zbase = ze + (size_t)b * NC * NK + k0;

    // ---- (1) t1 FIRST: numpy-exact chain (redundant x4, bit-identical).
    // Loads are fully coalesced; latency overlaps af-build + pass 1. ---------
    float t1;
    {
        const int v = L;
        float rr[8];
#pragma unroll
        for (int q = 0; q < 8; q++) {
            float xx = zbase[(size_t)q * NK + v];
            rr[q] = __fmul_rn(xx, xx);
        }
#pragma unroll
        for (int i = 8; i < 64; i += 8)
#pragma unroll
            for (int q = 0; q < 8; q++) {
                float xx = zbase[(size_t)(i + q) * NK + v];
                rr[q] = __fadd_rn(rr[q], __fmul_rn(xx, xx));
            }
        float s01 = __fadd_rn(rr[0], rr[1]), s23 = __fadd_rn(rr[2], rr[3]);
        float s45 = __fadd_rn(rr[4], rr[5]), s67 = __fadd_rn(rr[6], rr[7]);
        t1 = __fadd_rn(__fadd_rn(s01, s23), __fadd_rn(s45, s67));
    }

    // ---- A-frags for all 64 vectors (reg-resident, 32 VGPR) ----------------
    bf16x8 af[4][2];
#pragma unroll
    for (int vt = 0; vt < 4; vt++)
#pragma unroll
        for (int kt = 0; kt < 2; kt++)
#pragma unroll
            for (int j = 0; j < 8; j++)
                af[vt][kt][j] =
                    (__bf16)zbase[(size_t)(kt*32 + quad*8 + j) * NK + vt*16 + col];

    // ---- pass 1: per-lane proxy min over wave's 256 codes ------------------
    float pmin[4][4];
#pragma unroll
    for (int vt = 0; vt < 4; vt++)
#pragma unroll
        for (int r = 0; r < 4; r++) pmin[vt][r] = 1e30f;
#pragma unroll 4
    for (int tile = 0; tile < 16; tile++) {   // unroll 4: limit B-load hoisting
        const __bf16* brow = cbbf + (size_t)(w*256 + tile*16 + col) * NC + quad*8;
        bf16x8 b0 = *(const bf16x8*)(brow);
        bf16x8 b1 = *(const bf16x8*)(brow + 32);
        float nvv = n32[w*256 + tile*16 + col];
#pragma unroll
        for (int vt = 0; vt < 4; vt++) {   // 4 independent MFMA chains (ILP)
            f32x4 acc = {0.f, 0.f, 0.f, 0.f};
            acc = MFMA16(af[vt][0], b0, acc);
            acc = MFMA16(af[vt][1], b1, acc);
#pragma unroll
            for (int r = 0; r < 4; r++) {
                float pd = __fmaf_rn(-2.f, acc[r], nvv);  // == sub(nvv,mul(2,acc))
                pmin[vt][r] = fminf(pmin[vt][r], pd);
            }
        }
    }
    // one-time cross-col reduce
#pragma unroll
    for (int vt = 0; vt < 4; vt++)
#pragma unroll
        for (int r = 0; r < 4; r++) {
            float pm = pmin[vt][r];
            pm = fminf(pm, __shfl_xor(pm, 1, 16));
            pm = fminf(pm, __shfl_xor(pm, 2, 16));
            pm = fminf(pm, __shfl_xor(pm, 4, 16));
            pm = fminf(pm, __shfl_xor(pm, 8, 16));
            if (col == 0) wmin[vt*16 + quad*4 + r][w] = pm;
        }
    __syncthreads();

    if (t < 64) {
        float g = wmin[t][0];
#pragma unroll
        for (int ww = 1; ww < 4; ww++) g = fminf(g, wmin[t][ww]);
        gthr[t] = g + MARGIN;
        cnt[t] = 0;
    }
    __syncthreads();

    // ---- pass 2: capture candidates within MARGIN of global proxy min ------
    float thr[4][4];
#pragma unroll
    for (int vt = 0; vt < 4; vt++)
#pragma unroll
        for (int r = 0; r < 4; r++) thr[vt][r] = gthr[vt*16 + quad*4 + r];
#pragma unroll 4
    for (int tile = 0; tile < 16; tile++) {
        const __bf16* brow = cbbf + (size_t)(w*256 + tile*16 + col) * NC + quad*8;
        bf16x8 b0 = *(const bf16x8*)(brow);
        bf16x8 b1 = *(const bf16x8*)(brow + 32);
        float nvv = n32[w*256 + tile*16 + col];
#pragma unroll
        for (int vt = 0; vt < 4; vt++) {
            f32x4 acc = {0.f, 0.f, 0.f, 0.f};
            acc = MFMA16(af[vt][0], b0, acc);
            acc = MFMA16(af[vt][1], b1, acc);
#pragma unroll
            for (int r = 0; r < 4; r++) {
                float pd = __fmaf_rn(-2.f, acc[r], nvv);
                if (pd <= thr[vt][r]) {
                    int m = vt*16 + quad*4 + r;
                    int slot = atomicAdd(&cnt[m], 1);
                    if (slot < CAP) cand[m][slot] = w*256 + tile*16 + col;
                }
            }
        }
    }
    __syncthreads();

    // ---- (2) hoist epilogue z loads (code-independent; consumed later) -----
    const int c0e = t >> 4;            // 0..15
    const int v0e = (t & 15) * 4;      // 0,4,..,60
    f32x4 zpre[4];
#pragma unroll
    for (int half = 0; half < 4; half++)
        zpre[half] = *(const f32x4*)(zbase + (size_t)(c0e + half * 16) * NK + v0e);

    // ---- exact rescore: 4 threads/vector, validated bit-exact fp32 chain ---
    {
        const int v = L;               // vector; this thread handles part w
        int cc = cnt[v];
        unsigned long long kmin = 0xFFFFFFFFFFFFFFFFULL;
        if (cc <= CAP) {
            for (int si = w; si < cc; si += 4) {
                int j = cand[v][si];
                const float* cr = cb + (size_t)j * NC;
                float a = 0.f;
#pragma unroll
                for (int c = 0; c < NC; c++)
                    a = __fmaf_rn(zbase[(size_t)c * NK + v], cr[c], a);
                float d = __fmaf_rn(-2.f, a, __fadd_rn(t1, n32[j]));
                unsigned long long key =
                    ((unsigned long long)__float_as_uint(d) << 32) | (unsigned int)j;
                if (key < kmin) kmin = key;
            }
        } else {   // overflow fallback: exact full scan split over 4 threads
            for (int j = w * 256; j < (w + 1) * 256; j++) {
                const float* cr = cb + (size_t)j * NC;
                float a = 0.f;
#pragma unroll
                for (int c = 0; c < NC; c++)
                    a = __fmaf_rn(zbase[(size_t)c * NK + v], cr[c], a);
                float d = __fmaf_rn(-2.f, a, __fadd_rn(t1, n32[j]));
                unsigned long long key =
                    ((unsigned long long)__float_as_uint(d) << 32) | (unsigned int)j;
                if (key < kmin) kmin = key;
            }
        }
        keys2[v][w] = kmin;
    }
    __syncthreads();

    if (t < 64) {   // merge 4 partial keys: min dist, ties -> min idx (np rule)
        unsigned long long kmin = keys2[t][0];
#pragma unroll
        for (int ww = 1; ww < 4; ww++) {
            unsigned long long kk = keys2[t][ww];
            if (kk < kmin) kmin = kk;
        }
        int code = (int)(kmin & 0xFFFFFFFFu);
        codearr[t] = code;
        codes_f[vec0 + t] = (float)code;
        atomicAdd(&hist[code], 1);
    }
    __syncthreads();

    // ---- quant epilogue: uses preloaded zpre; float4 256B-contiguous stores
    double s = 0.0;
    float* ob = outq + (size_t)b * NC * NK + k0;
    int cds[4];
#pragma unroll
    for (int u = 0; u < 4; u++) cds[u] = codearr[v0e + u];
#pragma unroll
    for (int half = 0; half < 4; half++) {
        const int c = c0e + half * 16;
        f32x4 zv = zpre[half];
        f32x4 ov;
#pragma unroll
        for (int u = 0; u < 4; u++) {
            float qv = cb[(size_t)cds[u] * NC + c];
            ov[u] = __fadd_rn(zv[u], __fsub_rn(qv, zv[u]));
            double d = (double)qv - (double)zv[u];
            s += d * d;
        }
        *(f32x4*)(ob + (size_t)c * NK + v0e) = ov;
    }
    for (int off = 32; off; off >>= 1) s += __shfl_down(s, off);
    if (L == 0) lsd[w] = s;
    __syncthreads();
    if (t == 0) part[blockIdx.x] = lsd[0] + lsd[1] + lsd[2] + lsd[3];
}

// --- final scalars: loss_vq and perplexity (separate dispatch: R8 lesson) ---
__launch_bounds__(1024)
__global__ void k_final(const double* __restrict__ part, const int* __restrict__ hist,
                        float* __restrict__ out) {
    int t = threadIdx.x;                         // 1024 threads = NBLK partials
    double vL = part[t];
    double p = (double)hist[t] * (1.0 / (double)NVEC);
    double vE = p * log(p + 1e-10);
    for (int off = 32; off; off >>= 1) {
        vL += __shfl_down(vL, off);
        vE += __shfl_down(vE, off);
    }
    __shared__ double lsL[16], lsE[16];
    int lane = t & 63, wv = t >> 6;
    if (lane == 0) { lsL[wv] = vL; lsE[wv] = vE; }
    __syncthreads();
    if (t == 0) {
        double SL = 0.0, SE = 0.0;
        for (int i = 0; i < 16; i++) { SL += lsL[i]; SE += lsE[i]; }
        double loss_cb = SL / (double)NELEM;     // == loss_commit numerically
        out[NELEM + NVEC]     = (float)(loss_cb + 0.25 * loss_cb);
        out[NELEM + NVEC + 1] = (float)exp(-SE);
    }
}

extern "C" void kernel_launch(void* const* d_in, const int* in_sizes, int n_in,
                              void* d_out, int out_size, void* d_ws, size_t ws_size,
                              hipStream_t stream) {
    const float* ze = (const float*)d_in[0];
    const float* cb = (const float*)d_in[1];
    float* out = (float*)d_out;
    char* ws = (char*)d_ws;

    int*    hist = (int*)(ws + WS_HIST);
    float*  n32  = (float*)(ws + WS_CBN32);
    double* part = (double*)(ws + WS_PART);
    __bf16* cbbf = (__bf16*)(ws + WS_CBBF);

    float* zq      = out;                 // (32, 64, 2048)
    float* codes_f = out + NELEM;         // (32, 2048) as float

    k_cbprep<<<16, 64, 0, stream>>>(cb, n32, cbbf, hist);   // also zeroes hist
    k_vq<<<NBLK, 256, 0, stream>>>(ze, cb, n32, cbbf, hist, codes_f, zq, part);
    k_final<<<1, 1024, 0, stream>>>(part, hist, out);
}

// Round 13
// 125.406 us; speedup vs baseline: 4.6964x; 1.6120x over previous
//
#include <hip/hip_runtime.h>
#include <math.h>

// Problem constants
#define NB 32
#define NC 64          // CODE_DIM
#define NK 2048
#define NCODES 1024
#define NVEC (NB*NK)          // 65536 vectors
#define NELEM (NB*NC*NK)      // 4194304 elements
#define NBLK (NVEC/64)        // 1024 blocks

#define MARGIN 1.5e-3f        // rigorous bf16-proxy bound (validated R5)
#define CAP 32

// ws layout (bytes)
#define WS_HIST  0            // int[1024]      = 4096
#define WS_CBN32 4096         // float[1024]    = 4096
#define WS_PART  8192         // double[1024]   = 8192
#define WS_CBBF  32768        // __bf16[65536]  = 131072

typedef __bf16 bf16x8 __attribute__((ext_vector_type(8)));
typedef float  f32x4  __attribute__((ext_vector_type(4)));
#define MFMA16(A, B, ACC) __builtin_amdgcn_mfma_f32_16x16x32_bf16(A, B, ACC, 0, 0, 0)

// --- codebook prep: numpy-exact fp32 norms (same summation order as validated
// version -> bit-identical n32) + bf16 copy; block 0 zeroes hist. ------------
__global__ void k_cbprep(const float* __restrict__ cb, float* __restrict__ n32,
                         __bf16* __restrict__ cbbf, int* __restrict__ hist) {
    const int t = threadIdx.x;
    const int j = blockIdx.x * 64 + t;   // 16 x 64 = 1024
    if (blockIdx.x == 0) {
        int4 z4; z4.x = 0; z4.y = 0; z4.z = 0; z4.w = 0;
#pragma unroll
        for (int i = 0; i < 4; i++) ((int4*)hist)[t * 4 + i] = z4;
    }
    const float* cr = cb + (size_t)j * NC;
    float x[64];
#pragma unroll
    for (int i = 0; i < 16; i++) {
        f32x4 tv = *(const f32x4*)(cr + 4 * i);
        x[4*i+0] = tv[0]; x[4*i+1] = tv[1]; x[4*i+2] = tv[2]; x[4*i+3] = tv[3];
    }
    // EXACT same chain as validated version (order preserved)
    float r[8];
#pragma unroll
    for (int q = 0; q < 8; q++) r[q] = __fmul_rn(x[q], x[q]);
#pragma unroll
    for (int i = 8; i < 64; i += 8)
#pragma unroll
        for (int q = 0; q < 8; q++)
            r[q] = __fadd_rn(r[q], __fmul_rn(x[i + q], x[i + q]));
    float s01 = __fadd_rn(r[0], r[1]), s23 = __fadd_rn(r[2], r[3]);
    float s45 = __fadd_rn(r[4], r[5]), s67 = __fadd_rn(r[6], r[7]);
    n32[j] = __fadd_rn(__fadd_rn(s01, s23), __fadd_rn(s45, s67));
    __bf16* br = cbbf + (size_t)j * NC;
#pragma unroll
    for (int i = 0; i < 8; i++) {
        bf16x8 o;
#pragma unroll
        for (int q = 0; q < 8; q++) o[q] = (__bf16)x[8*i + q];
        *(bf16x8*)(br + 8*i) = o;
    }
}

// --- fused VQ: single-MFMA-pass via (min1,min2,idx1) tracking ----------------
// Block: 256 thr = 4 waves; 64 vectors; grid 1024 (measured-best shape).
// SESSION-BEST configuration (125.4us total, 61.8us k_vq) -- locked in.
// Pass 1 tracks per lane per (vt,r): min1, min2, idx1 (strict-lt update ->
// first-wins ties -> numpy rule preserved through exact rescore). candidates =
// {idx1 | min1 <= gthr}; complete unless some lane's min2 <= gthr (>=2 near-
// ties in one lane-column) -- then a block-uniform CHEAP in-block MFMA
// fallback re-runs the capture pass for flagged vectors (R11 lesson: the
// fallback must be an MFMA pass, never a per-vector serial scan).
// Evidence from this session: halving MFMA/L2 work (this kernel) and +22MB
// spill traffic both change duration ~0 -> kernel is phase-latency-bound;
// every structural lever tried (occupancy reshapes R1/R4/R5/R6, LDS staging
// R3, load hoisting R12, fused finalize R8) regressed. Separate k_final
// dispatch (R8: per-block device fence = per-block L2 writeback, +29us).
// MFMA 16x16x32 bf16 layout (validated R5): A[m=lane&15][k=quad*8+j];
// B[n=lane&15][k=quad*8+j]; D col=lane&15 (code), row=quad*4+reg (vector).
__launch_bounds__(256, 4)
__global__ void k_vq(const float* __restrict__ ze, const float* __restrict__ cb,
                     const float* __restrict__ n32, const __bf16* __restrict__ cbbf,
                     int* __restrict__ hist, float* __restrict__ codes_f,
                     float* __restrict__ outq, double* __restrict__ part) {
    __shared__ float wmin[64][5];            // padded minor (bank spread)
    __shared__ float gthr[64];
    __shared__ int cnt[64];
    __shared__ int needv[64];
    __shared__ int blockneed;
    __shared__ int cand[64][CAP + 1];        // padded
    __shared__ unsigned long long keys2[64][5];  // padded
    __shared__ int codearr[64];
    __shared__ double lsd[4];

    const int t = threadIdx.x;
    const int L = t & 63;
    const int w = t >> 6;            // wave 0..3
    const int quad = L >> 4;
    const int col = L & 15;
    const int vec0 = blockIdx.x * 64;
    const int b = vec0 >> 11;
    const int k0 = vec0 & (NK - 1);
    const float* zbase = ze + (size_t)b * NC * NK + k0;

    // ---- A-frags for all 64 vectors (reg-resident, 32 VGPR) ----------------
    bf16x8 af[4][2];
#pragma unroll
    for (int vt = 0; vt < 4; vt++)
#pragma unroll
        for (int kt = 0; kt < 2; kt++)
#pragma unroll
            for (int j = 0; j < 8; j++)
                af[vt][kt][j] =
                    (__bf16)zbase[(size_t)(kt*32 + quad*8 + j) * NK + vt*16 + col];

    // ---- single pass: per-lane (min1, min2, idx1) over wave's 256 codes ----
    float m1[4][4], m2[4][4];
    int   i1[4][4];
#pragma unroll
    for (int vt = 0; vt < 4; vt++)
#pragma unroll
        for (int r = 0; r < 4; r++) {
            m1[vt][r] = 1e30f; m2[vt][r] = 1e30f; i1[vt][r] = 0;
        }
#pragma unroll 4
    for (int tile = 0; tile < 16; tile++) {   // unroll 4: limit B-load hoisting
        const __bf16* brow = cbbf + (size_t)(w*256 + tile*16 + col) * NC + quad*8;
        bf16x8 b0 = *(const bf16x8*)(brow);
        bf16x8 b1 = *(const bf16x8*)(brow + 32);
        float nvv = n32[w*256 + tile*16 + col];
        const int code = w*256 + tile*16 + col;
#pragma unroll
        for (int vt = 0; vt < 4; vt++) {   // 4 independent MFMA chains (ILP)
            f32x4 acc = {0.f, 0.f, 0.f, 0.f};
            acc = MFMA16(af[vt][0], b0, acc);
            acc = MFMA16(af[vt][1], b1, acc);
#pragma unroll
            for (int r = 0; r < 4; r++) {
                float pd = __fmaf_rn(-2.f, acc[r], nvv);  // == sub(nvv,mul(2,acc))
                bool lt = pd < m1[vt][r];                 // strict: first-wins ties
                float nm2 = fminf(m2[vt][r], pd);
                m2[vt][r] = lt ? m1[vt][r] : nm2;
                i1[vt][r] = lt ? code : i1[vt][r];
                m1[vt][r] = lt ? pd : m1[vt][r];
            }
        }
    }
    // one-time cross-col reduce of min1 (value only; idx resolved by rescore)
#pragma unroll
    for (int vt = 0; vt < 4; vt++)
#pragma unroll
        for (int r = 0; r < 4; r++) {
            float pm = m1[vt][r];
            pm = fminf(pm, __shfl_xor(pm, 1, 16));
            pm = fminf(pm, __shfl_xor(pm, 2, 16));
            pm = fminf(pm, __shfl_xor(pm, 4, 16));
            pm = fminf(pm, __shfl_xor(pm, 8, 16));
            if (col == 0) wmin[vt*16 + quad*4 + r][w] = pm;
        }
    __syncthreads();

    if (t < 64) {
        float g = wmin[t][0];
#pragma unroll
        for (int ww = 1; ww < 4; ww++) g = fminf(g, wmin[t][ww]);
        gthr[t] = g + MARGIN;
        cnt[t] = 0;
        needv[t] = 0;
    }
    if (t == 0) blockneed = 0;
    __syncthreads();

    // ---- candidate insertion from registers (no second codebook pass) ------
#pragma unroll
    for (int vt = 0; vt < 4; vt++)
#pragma unroll
        for (int r = 0; r < 4; r++) {
            const int m = vt*16 + quad*4 + r;
            const float thr = gthr[m];
            if (m1[vt][r] <= thr) {
                int slot = atomicAdd(&cnt[m], 1);
                if (slot < CAP) cand[m][slot] = i1[vt][r];
            }
            if (m2[vt][r] <= thr) { needv[m] = 1; blockneed = 1; }
        }
    __syncthreads();

    // ---- fallback capture pass (rare: >=2 near-ties within one lane) -------
    if (blockneed) {
        if (t < 64 && needv[t]) cnt[t] = 0;
        __syncthreads();
#pragma unroll 4
        for (int tile = 0; tile < 16; tile++) {
            const __bf16* brow = cbbf + (size_t)(w*256 + tile*16 + col) * NC + quad*8;
            bf16x8 b0 = *(const bf16x8*)(brow);
            bf16x8 b1 = *(const bf16x8*)(brow + 32);
            float nvv = n32[w*256 + tile*16 + col];
#pragma unroll
            for (int vt = 0; vt < 4; vt++) {
                f32x4 acc = {0.f, 0.f, 0.f, 0.f};
                acc = MFMA16(af[vt][0], b0, acc);
                acc = MFMA16(af[vt][1], b1, acc);
#pragma unroll
                for (int r = 0; r < 4; r++) {
                    const int m = vt*16 + quad*4 + r;
                    if (needv[m]) {
                        float pd = __fmaf_rn(-2.f, acc[r], nvv);
                        if (pd <= gthr[m]) {
                            int slot = atomicAdd(&cnt[m], 1);
                            if (slot < CAP) cand[m][slot] = w*256 + tile*16 + col;
                        }
                    }
                }
            }
        }
        __syncthreads();
    }

    // ---- exact rescore: 4 threads/vector, validated bit-exact fp32 chain ---
    {
        const int v = L;           // vector; this thread handles part w
        // t1 = np.sum(z*z), numpy-exact (redundant x4, bit-identical -- R2)
        float rr[8];
#pragma unroll
        for (int q = 0; q < 8; q++) {
            float xx = zbase[(size_t)q * NK + v];
            rr[q] = __fmul_rn(xx, xx);
        }
#pragma unroll
        for (int i = 8; i < 64; i += 8)
#pragma unroll
            for (int q = 0; q < 8; q++) {
                float xx = zbase[(size_t)(i + q) * NK + v];
                rr[q] = __fadd_rn(rr[q], __fmul_rn(xx, xx));
            }
        float s01 = __fadd_rn(rr[0], rr[1]), s23 = __fadd_rn(rr[2], rr[3]);
        float s45 = __fadd_rn(rr[4], rr[5]), s67 = __fadd_rn(rr[6], rr[7]);
        float t1 = __fadd_rn(__fadd_rn(s01, s23), __fadd_rn(s45, s67));

        int cc = cnt[v];
        unsigned long long kmin = 0xFFFFFFFFFFFFFFFFULL;
        if (cc <= CAP) {
            for (int si = w; si < cc; si += 4) {
                int j = cand[v][si];
                const float* cr = cb + (size_t)j * NC;
                float a = 0.f;
#pragma unroll
                for (int c = 0; c < NC; c++)
                    a = __fmaf_rn(zbase[(size_t)c * NK + v], cr[c], a);
                float d = __fmaf_rn(-2.f, a, __fadd_rn(t1, n32[j]));
                unsigned long long key =
                    ((unsigned long long)__float_as_uint(d) << 32) | (unsigned int)j;
                if (key < kmin) kmin = key;
            }
        } else {   // overflow fallback: exact full scan split over 4 threads
            for (int j = w * 256; j < (w + 1) * 256; j++) {
                const float* cr = cb + (size_t)j * NC;
                float a = 0.f;
#pragma unroll
                for (int c = 0; c < NC; c++)
                    a = __fmaf_rn(zbase[(size_t)c * NK + v], cr[c], a);
                float d = __fmaf_rn(-2.f, a, __fadd_rn(t1, n32[j]));
                unsigned long long key =
                    ((unsigned long long)__float_as_uint(d) << 32) | (unsigned int)j;
                if (key < kmin) kmin = key;
            }
        }
        keys2[v][w] = kmin;
    }
    __syncthreads();

    if (t < 64) {   // merge 4 partial keys: min dist, ties -> min idx (np rule)
        unsigned long long kmin = keys2[t][0];
#pragma unroll
        for (int ww = 1; ww < 4; ww++) {
            unsigned long long kk = keys2[t][ww];
            if (kk < kmin) kmin = kk;
        }
        int code = (int)(kmin & 0xFFFFFFFFu);
        codearr[t] = code;
        codes_f[vec0 + t] = (float)code;
        atomicAdd(&hist[code], 1);
    }
    __syncthreads();

    // ---- quant epilogue: float4; per c-row 16 thr x 16B = 256B contiguous --
    double s = 0.0;
    float* ob = outq + (size_t)b * NC * NK + k0;
    const int c0 = t >> 4;             // 0..15
    const int v0 = (t & 15) * 4;       // 0,4,..,60
    int cds[4];
#pragma unroll
    for (int u = 0; u < 4; u++) cds[u] = codearr[v0 + u];
#pragma unroll
    for (int half = 0; half < 4; half++) {
        const int c = c0 + half * 16;
        f32x4 zv = *(const f32x4*)(zbase + (size_t)c * NK + v0);
        f32x4 ov;
#pragma unroll
        for (int u = 0; u < 4; u++) {
            float qv = cb[(size_t)cds[u] * NC + c];
            ov[u] = __fadd_rn(zv[u], __fsub_rn(qv, zv[u]));
            double d = (double)qv - (double)zv[u];
            s += d * d;
        }
        *(f32x4*)(ob + (size_t)c * NK + v0) = ov;
    }
    for (int off = 32; off; off >>= 1) s += __shfl_down(s, off);
    if (L == 0) lsd[w] = s;
    __syncthreads();
    if (t == 0) part[blockIdx.x] = lsd[0] + lsd[1] + lsd[2] + lsd[3];
}

// --- final scalars: loss_vq and perplexity (separate dispatch: R8 lesson) ---
__launch_bounds__(1024)
__global__ void k_final(const double* __restrict__ part, const int* __restrict__ hist,
                        float* __restrict__ out) {
    int t = threadIdx.x;                         // 1024 threads = NBLK partials
    double vL = part[t];
    double p = (double)hist[t] * (1.0 / (double)NVEC);
    double vE = p * log(p + 1e-10);
    for (int off = 32; off; off >>= 1) {
        vL += __shfl_down(vL, off);
        vE += __shfl_down(vE, off);
    }
    __shared__ double lsL[16], lsE[16];
    int lane = t & 63, wv = t >> 6;
    if (lane == 0) { lsL[wv] = vL; lsE[wv] = vE; }
    __syncthreads();
    if (t == 0) {
        double SL = 0.0, SE = 0.0;
        for (int i = 0; i < 16; i++) { SL += lsL[i]; SE += lsE[i]; }
        double loss_cb = SL / (double)NELEM;     // == loss_commit numerically
        out[NELEM + NVEC]     = (float)(loss_cb + 0.25 * loss_cb);
        out[NELEM + NVEC + 1] = (float)exp(-SE);
    }
}

extern "C" void kernel_launch(void* const* d_in, const int* in_sizes, int n_in,
                              void* d_out, int out_size, void* d_ws, size_t ws_size,
                              hipStream_t stream) {
    const float* ze = (const float*)d_in[0];
    const float* cb = (const float*)d_in[1];
    float* out = (float*)d_out;
    char* ws = (char*)d_ws;

    int*    hist = (int*)(ws + WS_HIST);
    float*  n32  = (float*)(ws + WS_CBN32);
    double* part = (double*)(ws + WS_PART);
    __bf16* cbbf = (__bf16*)(ws + WS_CBBF);

    float* zq      = out;                 // (32, 64, 2048)
    float* codes_f = out + NELEM;         // (32, 2048) as float

    k_cbprep<<<16, 64, 0, stream>>>(cb, n32, cbbf, hist);   // also zeroes hist
    k_vq<<<NBLK, 256, 0, stream>>>(ze, cb, n32, cbbf, hist, codes_f, zq, part);
    k_final<<<1, 1024, 0, stream>>>(part, hist, out);
}